// Round 1
// baseline (632.979 us; speedup 1.0000x reference)
//
#include <hip/hip_runtime.h>

#define NB 4
#define SEQ 4096
#define DM 512
#define DA 64

typedef __attribute__((ext_vector_type(8))) short bf16x8;
typedef __attribute__((ext_vector_type(4))) float f32x4;

__device__ __forceinline__ unsigned short f2bf(float f) {
  unsigned u = __float_as_uint(f);
  u += 0x7fffu + ((u >> 16) & 1u);
  return (unsigned short)(u >> 16);
}

// ---------------- Kernel 1: cast x (f32) -> xb (bf16) ----------------
__global__ void cast_x_kernel(const float* __restrict__ x, unsigned short* __restrict__ xb) {
  size_t i = ((size_t)blockIdx.x * blockDim.x + threadIdx.x) * 4;  // 4 floats/thread
  float4 v = *(const float4*)(x + i);
  ushort4 o;
  o.x = f2bf(v.x); o.y = f2bf(v.y); o.z = f2bf(v.z); o.w = f2bf(v.w);
  *(ushort4*)(xb + i) = o;
}

// ------------- Kernel 2: build Wt[640][512] bf16 (transposed) + bias[640] -------------
__global__ void prep_w_kernel(const float* __restrict__ Wq, const float* __restrict__ bq,
                              const float* __restrict__ Wk, const float* __restrict__ bk,
                              const float* __restrict__ Wv, const float* __restrict__ bv,
                              unsigned short* __restrict__ Wt, float* __restrict__ bias) {
  int n = blockIdx.x;  // 0..639
  for (int k = threadIdx.x; k < DM; k += blockDim.x) {
    float w;
    if (n < 64)       w = Wq[(size_t)k * DA + n];
    else if (n < 128) w = Wk[(size_t)k * DA + (n - 64)];
    else              w = Wv[(size_t)k * DM + (n - 128)];
    Wt[(size_t)n * DM + k] = f2bf(w);
  }
  if (threadIdx.x == 0)
    bias[n] = (n < 64) ? bq[n] : (n < 128) ? bk[n - 64] : bv[n - 128];
}

// ------------- Kernel 3: projection GEMM  out[16384 x 640] = xb @ Wt^T + bias -------------
// outputs scattered: n<64 -> q[S][64], n<128 -> k[S][64], else vt[512][S] (transposed V)
__launch_bounds__(256)
__global__ void proj_kernel(const unsigned short* __restrict__ xb,
                            const unsigned short* __restrict__ Wt,
                            const float* __restrict__ bias,
                            unsigned short* __restrict__ qws,
                            unsigned short* __restrict__ kws,
                            unsigned short* __restrict__ vt) {
  int ctb = blockIdx.x;   // 0..9   (64-col tile)
  int rtb = blockIdx.y;   // 0..255 (64-row tile)
  int tid = threadIdx.x;
  int wid = tid >> 6, lane = tid & 63;
  int g = lane >> 4, c15 = lane & 15;
  int wr = wid >> 1, wc = wid & 1;
  int rbase = rtb * 64 + wr * 32;
  int cbase = ctb * 64 + wc * 32;

  f32x4 acc[2][2];
  for (int i = 0; i < 2; i++) for (int j = 0; j < 2; j++) acc[i][j] = (f32x4)0.0f;

  for (int kk = 0; kk < DM; kk += 32) {
    bf16x8 a[2], bb[2];
    for (int i = 0; i < 2; i++)
      a[i] = *(const bf16x8*)(xb + (size_t)(rbase + i * 16 + c15) * DM + kk + g * 8);
    for (int j = 0; j < 2; j++)
      bb[j] = *(const bf16x8*)(Wt + (size_t)(cbase + j * 16 + c15) * DM + kk + g * 8);
    for (int i = 0; i < 2; i++)
      for (int j = 0; j < 2; j++)
        acc[i][j] = __builtin_amdgcn_mfma_f32_16x16x32_bf16(a[i], bb[j], acc[i][j], 0, 0, 0);
  }

  for (int i = 0; i < 2; i++) {
    for (int j = 0; j < 2; j++) {
      int n = cbase + j * 16 + c15;
      float bv_ = bias[n];
      for (int r = 0; r < 4; r++) {
        int R = rbase + i * 16 + g * 4 + r;     // global row in [0,16384)
        float val = acc[i][j][r] + bv_;
        unsigned short h = f2bf(val);
        if (n < 64)        qws[(size_t)R * DA + n] = h;
        else if (n < 128)  kws[(size_t)R * DA + (n - 64)] = h;
        else {
          int b = R >> 12, s = R & (SEQ - 1);
          vt[((size_t)b * DM + (n - 128)) * SEQ + s] = h;
        }
      }
    }
  }
}

// ------------- Kernel 4: causal flash attention -------------
// BLOCK_M=32 q rows, 8 waves: wave = (rh in 0..1 [16-row stripe], wc in 0..3 [128 d_v cols])
// per iter: 128 keys. S computed in disjoint 16x32 slices; stats combined in LDS; P staged in LDS.
__launch_bounds__(512)
__global__ void attn_kernel(const unsigned short* __restrict__ qws,
                            const unsigned short* __restrict__ kws,
                            const unsigned short* __restrict__ vt,
                            float* __restrict__ ows) {
  int b = blockIdx.y;
  int bx = blockIdx.x;
  int qblk = (bx & 1) ? (127 - (bx >> 1)) : (bx >> 1);  // pair long+short blocks
  int qbase = qblk * 32;
  int tid = threadIdx.x;
  int wid = tid >> 6, lane = tid & 63;
  int g = lane >> 4, c15 = lane & 15;
  int rh = wid & 1, wc = wid >> 1;
  int qrow16 = qbase + rh * 16;

  __shared__ float lds_pmax[4][32];
  __shared__ float lds_psum[4][32];
  __shared__ __align__(16) unsigned short lds_P[32][136];  // stride 272B: 16B-aligned, 2-way banks

  bf16x8 qf[2];
  for (int kc = 0; kc < 2; kc++)
    qf[kc] = *(const bf16x8*)(qws + ((size_t)b * SEQ + qrow16 + c15) * DA + kc * 32 + g * 8);

  f32x4 acc[8];
  for (int n = 0; n < 8; n++) acc[n] = (f32x4)0.0f;
  float m_run[4], l_run[4];
  for (int r = 0; r < 4; r++) { m_run[r] = -1e30f; l_run[r] = 0.0f; }

  int nkt = (qbase + 32 + 127) / 128;

  for (int kt = 0; kt < nkt * 128; kt += 128) {
    // ---- S slice: rows [qrow16,+16) x keys [kt+wc*32,+32) ----
    f32x4 sc[2];
    sc[0] = (f32x4)0.0f; sc[1] = (f32x4)0.0f;
    for (int kc = 0; kc < 2; kc++) {
      for (int ct = 0; ct < 2; ct++) {
        int key = kt + wc * 32 + ct * 16 + c15;
        bf16x8 kf = *(const bf16x8*)(kws + ((size_t)b * SEQ + key) * DA + kc * 32 + g * 8);
        sc[ct] = __builtin_amdgcn_mfma_f32_16x16x32_bf16(qf[kc], kf, sc[ct], 0, 0, 0);
      }
    }
    // ---- causal mask + per-wave row max ----
    float pm[4];
    for (int r = 0; r < 4; r++) {
      int qrow = qrow16 + g * 4 + r;
      for (int ct = 0; ct < 2; ct++) {
        int key = kt + wc * 32 + ct * 16 + c15;
        if (key > qrow) sc[ct][r] = -1e30f;
      }
      float mv = fmaxf(sc[0][r], sc[1][r]);
      mv = fmaxf(mv, __shfl_xor(mv, 1));
      mv = fmaxf(mv, __shfl_xor(mv, 2));
      mv = fmaxf(mv, __shfl_xor(mv, 4));
      mv = fmaxf(mv, __shfl_xor(mv, 8));
      pm[r] = mv;
    }
    if (c15 == 0)
      for (int r = 0; r < 4; r++) lds_pmax[wc][rh * 16 + g * 4 + r] = pm[r];
    __syncthreads();

    // ---- P = exp(S - m_new), partial row sums, stage P to LDS ----
    float mnew[4], ps4[4];
    for (int r = 0; r < 4; r++) {
      int row32 = rh * 16 + g * 4 + r;
      float tm = fmaxf(fmaxf(lds_pmax[0][row32], lds_pmax[1][row32]),
                       fmaxf(lds_pmax[2][row32], lds_pmax[3][row32]));
      float mn = fmaxf(m_run[r], tm);
      mnew[r] = mn;
      float s = 0.0f;
      for (int ct = 0; ct < 2; ct++) {
        float p = __expf(sc[ct][r] - mn);
        sc[ct][r] = p;
        s += p;
      }
      s += __shfl_xor(s, 1); s += __shfl_xor(s, 2);
      s += __shfl_xor(s, 4); s += __shfl_xor(s, 8);
      ps4[r] = s;
      for (int ct = 0; ct < 2; ct++)
        lds_P[row32][wc * 32 + ct * 16 + c15] = f2bf(sc[ct][r]);
    }
    if (c15 == 0)
      for (int r = 0; r < 4; r++) lds_psum[wc][rh * 16 + g * 4 + r] = ps4[r];
    __syncthreads();

    // ---- combine stats, rescale O, PV ----
    for (int r = 0; r < 4; r++) {
      int row32 = rh * 16 + g * 4 + r;
      float ts = lds_psum[0][row32] + lds_psum[1][row32] +
                 lds_psum[2][row32] + lds_psum[3][row32];
      float scl = __expf(m_run[r] - mnew[r]);
      m_run[r] = mnew[r];
      l_run[r] = l_run[r] * scl + ts;
      for (int n = 0; n < 8; n++) acc[n][r] *= scl;
    }
    for (int kc = 0; kc < 4; kc++) {
      bf16x8 pa = *(const bf16x8*)&lds_P[rh * 16 + c15][kc * 32 + g * 8];
      for (int n = 0; n < 8; n++) {
        int dv = wc * 128 + n * 16 + c15;
        bf16x8 vb = *(const bf16x8*)(vt + ((size_t)b * DM + dv) * SEQ + kt + kc * 32 + g * 8);
        acc[n] = __builtin_amdgcn_mfma_f32_16x16x32_bf16(pa, vb, acc[n], 0, 0, 0);
      }
    }
    __syncthreads();
  }

  // ---- epilogue: O = acc / l ----
  for (int n = 0; n < 8; n++) {
    int dv = wc * 128 + n * 16 + c15;
    for (int r = 0; r < 4; r++) {
      int qrow = qrow16 + g * 4 + r;
      ows[((size_t)b * SEQ + qrow) * DM + dv] = acc[n][r] / l_run[r];
    }
  }
}

// ------------- Kernel 5: residual + LayerNorm (wave per row) -------------
__launch_bounds__(256)
__global__ void ln_kernel(const float* __restrict__ x, const float* __restrict__ o,
                          const float* __restrict__ gamma, const float* __restrict__ beta,
                          float* __restrict__ out) {
  int wid = threadIdx.x >> 6, lane = threadIdx.x & 63;
  size_t row = (size_t)blockIdx.x * 4 + wid;  // 16384 rows
  size_t base = row * DM + lane * 8;
  float4 xa = *(const float4*)(x + base);
  float4 xb2 = *(const float4*)(x + base + 4);
  float4 oa = *(const float4*)(o + base);
  float4 ob = *(const float4*)(o + base + 4);
  float y[8] = {xa.x + oa.x, xa.y + oa.y, xa.z + oa.z, xa.w + oa.w,
                xb2.x + ob.x, xb2.y + ob.y, xb2.z + ob.z, xb2.w + ob.w};
  float s1 = 0.0f, s2 = 0.0f;
  for (int j = 0; j < 8; j++) { s1 += y[j]; s2 += y[j] * y[j]; }
  for (int m = 1; m < 64; m <<= 1) { s1 += __shfl_xor(s1, m); s2 += __shfl_xor(s2, m); }
  float mu = s1 * (1.0f / DM);
  float var = s2 * (1.0f / DM) - mu * mu;
  float rs = rsqrtf(var + 1e-5f);
  int c = lane * 8;
  for (int j = 0; j < 8; j++)
    out[base + j] = (y[j] - mu) * rs * gamma[c + j] + beta[c + j];
}

extern "C" void kernel_launch(void* const* d_in, const int* in_sizes, int n_in,
                              void* d_out, int out_size, void* d_ws, size_t ws_size,
                              hipStream_t stream) {
  const float* x     = (const float*)d_in[0];
  const float* Wq    = (const float*)d_in[1];
  const float* bq    = (const float*)d_in[2];
  const float* Wk    = (const float*)d_in[3];
  const float* bk    = (const float*)d_in[4];
  const float* Wv    = (const float*)d_in[5];
  const float* bv    = (const float*)d_in[6];
  const float* gamma = (const float*)d_in[7];
  const float* beta  = (const float*)d_in[8];
  float* out = (float*)d_out;

  char* ws = (char*)d_ws;
  // o (f32, 32MB) aliases xb (bf16, 16MB): xb is dead before attention writes o.
  float*          ows  = (float*)(ws + 0);
  unsigned short* xb   = (unsigned short*)(ws + 0);
  unsigned short* qws  = (unsigned short*)(ws + 33554432);
  unsigned short* kws  = (unsigned short*)(ws + 35651584);
  unsigned short* vt   = (unsigned short*)(ws + 37748736);
  unsigned short* Wt   = (unsigned short*)(ws + 54525952);
  float*          bias = (float*)(ws + 55181312);

  cast_x_kernel<<<8192, 256, 0, stream>>>(x, xb);
  prep_w_kernel<<<640, 256, 0, stream>>>(Wq, bq, Wk, bk, Wv, bv, Wt, bias);
  proj_kernel<<<dim3(10, 256), 256, 0, stream>>>(xb, Wt, bias, qws, kws, vt);
  attn_kernel<<<dim3(128, NB), 512, 0, stream>>>(qws, kws, vt, ows);
  ln_kernel<<<4096, 256, 0, stream>>>(x, ows, gamma, beta, out);
}